// Round 1
// baseline (450.106 us; speedup 1.0000x reference)
//
#include <hip/hip_runtime.h>
#include <hip/hip_bf16.h>
#include <math.h>

#define D_FEAT 128
#define ALPHA 0.2f
#define EPS 1e-8f

typedef __bf16 bf16x8 __attribute__((ext_vector_type(8)));
typedef __bf16 bf16x2 __attribute__((ext_vector_type(2)));
typedef float f32x4 __attribute__((ext_vector_type(4)));
typedef float f32x2 __attribute__((ext_vector_type(2)));
typedef int i32x4 __attribute__((ext_vector_type(4)));

// Split 8 consecutive f32 into hi/lo bf16 halves: x ~= hi + lo
__device__ __forceinline__ void split_bf16(const float* __restrict__ p,
                                           bf16x8& hi, bf16x8& lo)
{
    f32x4 a = *(const f32x4*)p;
    f32x4 b = *(const f32x4*)(p + 4);
#pragma unroll
    for (int j = 0; j < 4; ++j) {
        float x = a[j]; __bf16 xh = (__bf16)x;
        hi[j] = xh; lo[j] = (__bf16)(x - (float)xh);
        float y = b[j]; __bf16 yh = (__bf16)y;
        hi[j + 4] = yh; lo[j + 4] = (__bf16)(y - (float)yh);
    }
}

// ---------------------------------------------------------------------------
// K0: pre-split W (128x128 f32) into Whi/Wlo bf16 arrays (once per launch).
// ---------------------------------------------------------------------------
__global__ __launch_bounds__(256) void presplit_w(
    const float* __restrict__ W, __bf16* __restrict__ Whi, __bf16* __restrict__ Wlo)
{
    const int i = blockIdx.x * 256 + threadIdx.x;   // 64 blocks x 256 = 16384
    const float x = W[i];
    const __bf16 xh = (__bf16)x;
    Whi[i] = xh;
    Wlo[i] = (__bf16)(x - (float)xh);
}

// ---------------------------------------------------------------------------
// K1: Wh = h @ W^T via split-bf16 MFMA (f32-grade accumulators).
// ---------------------------------------------------------------------------
__global__ __launch_bounds__(256) void gemm_s_kernel(
    const float* __restrict__ h,
    const __bf16* __restrict__ Whi, const __bf16* __restrict__ Wlo,
    const float* __restrict__ a, __bf16* __restrict__ Whb,
    float* __restrict__ s_src, float* __restrict__ s_dst, int N)
{
    const int wave = threadIdx.x >> 6;
    const int lane = threadIdx.x & 63;
    const int row0 = blockIdx.x * 64 + wave * 16;
    if (row0 >= N) return;

    const int l15 = lane & 15;
    const int quad = lane >> 4;

    int arow = row0 + l15;
    if (arow >= N) arow = N - 1;
    bf16x8 ahi[4], alo[4];
#pragma unroll
    for (int kk = 0; kk < 4; ++kk)
        split_bf16(h + (size_t)arow * D_FEAT + kk * 32 + quad * 8, ahi[kk], alo[kk]);

    f32x4 acc[8];
#pragma unroll
    for (int n = 0; n < 8; ++n) acc[n] = (f32x4){0.f, 0.f, 0.f, 0.f};

#pragma unroll
    for (int kk = 0; kk < 4; ++kk) {
#pragma unroll
        for (int n = 0; n < 8; ++n) {
            const size_t boff = (size_t)(n * 16 + l15) * D_FEAT + kk * 32 + quad * 8;
            const bf16x8 bhi = *(const bf16x8*)(Whi + boff);
            const bf16x8 blo = *(const bf16x8*)(Wlo + boff);
            acc[n] = __builtin_amdgcn_mfma_f32_16x16x32_bf16(ahi[kk], bhi, acc[n], 0, 0, 0);
            acc[n] = __builtin_amdgcn_mfma_f32_16x16x32_bf16(ahi[kk], blo, acc[n], 0, 0, 0);
            acc[n] = __builtin_amdgcn_mfma_f32_16x16x32_bf16(alo[kk], bhi, acc[n], 0, 0, 0);
        }
    }

    float psrc[4] = {0.f, 0.f, 0.f, 0.f};
    float pdst[4] = {0.f, 0.f, 0.f, 0.f};
#pragma unroll
    for (int n = 0; n < 8; ++n) {
        const int col = n * 16 + l15;
        const float as = a[col];
        const float ad = a[D_FEAT + col];
#pragma unroll
        for (int r = 0; r < 4; ++r) {
            const int row = row0 + quad * 4 + r;
            const float v = acc[n][r];
            if (row < N) Whb[(size_t)row * D_FEAT + col] = (__bf16)v;
            psrc[r] += v * as;
            pdst[r] += v * ad;
        }
    }
#pragma unroll
    for (int off = 1; off < 16; off <<= 1) {
#pragma unroll
        for (int r = 0; r < 4; ++r) {
            psrc[r] += __shfl_xor(psrc[r], off, 64);
            pdst[r] += __shfl_xor(pdst[r], off, 64);
        }
    }
    if (l15 == 0) {
#pragma unroll
        for (int r = 0; r < 4; ++r) {
            const int row = row0 + quad * 4 + r;
            if (row < N) { s_src[row] = psrc[r]; s_dst[row] = pdst[r]; }
        }
    }
}

// ---------------------------------------------------------------------------
// hist: count[dst]++ (4 edges per thread, vector load).
// ---------------------------------------------------------------------------
__global__ __launch_bounds__(256) void hist_kernel(
    const int* __restrict__ dst, int* __restrict__ count, int E)
{
    const int i4 = (blockIdx.x * blockDim.x + threadIdx.x) * 4;
    if (i4 + 3 < E) {
        const int4 d = *(const int4*)(dst + i4);
        atomicAdd(count + d.x, 1);
        atomicAdd(count + d.y, 1);
        atomicAdd(count + d.z, 1);
        atomicAdd(count + d.w, 1);
    } else {
        for (int i = i4; i < E; ++i) atomicAdd(count + dst[i], 1);
    }
}

// ---------------------------------------------------------------------------
// Exclusive scan over count[0..N) -> row_ptr, 1024-element chunks.
// ---------------------------------------------------------------------------
__global__ __launch_bounds__(256) void scan_a(
    const int* __restrict__ count, int* __restrict__ row_ptr,
    int* __restrict__ blk_sums, int N)
{
    __shared__ int sh[256];
    const int t = threadIdx.x;
    const int base = blockIdx.x * 1024 + t * 4;
    int v[4];
#pragma unroll
    for (int k = 0; k < 4; ++k) v[k] = (base + k < N) ? count[base + k] : 0;
    const int ts = v[0] + v[1] + v[2] + v[3];
    sh[t] = ts;
    __syncthreads();
    for (int off = 1; off < 256; off <<= 1) {
        int x = (t >= off) ? sh[t - off] : 0;
        __syncthreads();
        sh[t] += x;
        __syncthreads();
    }
    int run = sh[t] - ts;
#pragma unroll
    for (int k = 0; k < 4; ++k) {
        if (base + k < N) row_ptr[base + k] = run;
        run += v[k];
    }
    if (t == 255) blk_sums[blockIdx.x] = sh[255];
}

__global__ __launch_bounds__(256) void scan_b(int* __restrict__ blk_sums, int nb)
{
    __shared__ int sh[256];
    const int t = threadIdx.x;
    const int v = (t < nb) ? blk_sums[t] : 0;
    sh[t] = v;
    __syncthreads();
    for (int off = 1; off < 256; off <<= 1) {
        int x = (t >= off) ? sh[t - off] : 0;
        __syncthreads();
        sh[t] += x;
        __syncthreads();
    }
    if (t < nb) blk_sums[t] = sh[t] - v;
}

__global__ __launch_bounds__(256) void scan_c(
    int* __restrict__ row_ptr, int* __restrict__ cursor,
    const int* __restrict__ blk_sums, int N, int E)
{
    const int base = blockIdx.x * 1024 + threadIdx.x * 4;
    const int add = blk_sums[blockIdx.x];
#pragma unroll
    for (int k = 0; k < 4; ++k) {
        const int i = base + k;
        if (i < N) {
            const int r = row_ptr[i] + add;
            row_ptr[i] = r;
            cursor[i] = r;
        }
    }
    if (blockIdx.x == 0 && threadIdx.x == 0) row_ptr[N] = E;
}

// ---------------------------------------------------------------------------
// comp_scatter, XCD-range-partitioned:
// Nodes are split into 8 dst-ranges (~N/8 nodes, ~E/8 * 8B ~ 1.6MB of `sorted`
// each). range = blockIdx & 7, so under round-robin dispatch each range's
// blocks land on ONE XCD, whose 4MB L2 holds the whole write region ->
// random 8B scatters coalesce in L2 into full-line writebacks (~13MB total
// instead of E*64B = 102MB). Every range group scans the full edge stream
// (nt loads: keep the 4MB L2 for the write set; the 256MB L3 holds the
// 19MB of edge data for the 8x re-read).
// ---------------------------------------------------------------------------
__global__ __launch_bounds__(256) void comp_scatter(
    const int* __restrict__ src, const int* __restrict__ dst,
    const float* __restrict__ ew,
    const float* __restrict__ s_src, const float* __restrict__ s_dst,
    int* __restrict__ cursor, uint2* __restrict__ sorted,
    int E, int N, int chunk)
{
    const int range = blockIdx.x & 7;
    const int g = blockIdx.x >> 3;
    const int lo = (range * N) >> 3;
    const int hi = ((range + 1) * N) >> 3;

    const int start = g * chunk;
    if (start >= E) return;
    const int stop = min(start + chunk, E);

    for (int i4 = start + ((int)threadIdx.x << 2); i4 < stop; i4 += 1024) {
        if (i4 + 3 < stop) {
            const i32x4 d4 = __builtin_nontemporal_load((const i32x4*)(dst + i4));
#pragma unroll
            for (int k = 0; k < 4; ++k) {
                const int d = d4[k];
                if (d >= lo && d < hi) {
                    const int i = i4 + k;
                    const int s = __builtin_nontemporal_load(src + i);
                    const float w = __builtin_nontemporal_load(ew + i);
                    float e = s_src[s] + s_dst[d];
                    e = (e >= 0.f) ? e : ALPHA * e;
                    e *= w;
                    const float ex = expf(e);
                    const int pos = atomicAdd(cursor + d, 1);
                    sorted[pos] = make_uint2((unsigned)s, __float_as_uint(ex));
                }
            }
        } else {
            for (int i = i4; i < stop; ++i) {
                const int d = dst[i];
                if (d >= lo && d < hi) {
                    const int s = src[i];
                    float e = s_src[s] + s_dst[d];
                    e = (e >= 0.f) ? e : ALPHA * e;
                    e *= ew[i];
                    const float ex = expf(e);
                    const int pos = atomicAdd(cursor + d, 1);
                    sorted[pos] = make_uint2((unsigned)s, __float_as_uint(ex));
                }
            }
        }
    }
}

// ---------------------------------------------------------------------------
// K4: gather aggregation, one wave per node, no atomics.
// ---------------------------------------------------------------------------
__global__ __launch_bounds__(256) void aggregate_csr(
    const int* __restrict__ row_ptr, const uint2* __restrict__ sorted,
    const __bf16* __restrict__ Whb, float* __restrict__ out, int N)
{
    const int wave = threadIdx.x >> 6;
    const int lane = threadIdx.x & 63;
    const int node = blockIdx.x * 4 + wave;
    if (node >= N) return;
    const int beg = row_ptr[node];
    const int end = row_ptr[node + 1];
    const int cnt = end - beg;

    // load up to 64 metas into registers (one per lane), coalesced
    int mx = 0; unsigned my = 0u;
    if (lane < cnt) {
        const uint2 m = sorted[beg + lane];
        mx = (int)m.x; my = m.y;
    }
    // seg_sum: register metas + (cold) strided loop for degree > 64
    float ssum = (lane < cnt) ? __uint_as_float(my) : 0.f;
    for (int j = beg + 64 + lane; j < end; j += 64)
        ssum += __uint_as_float(sorted[j].y);
#pragma unroll
    for (int off = 1; off < 64; off <<= 1)
        ssum += __shfl_xor(ssum, off, 64);
    const float inv = 1.f / (ssum + EPS);

    const int c0 = lane * 2;
    const int inreg = cnt < 64 ? cnt : 64;
    float ax = 0.f, ay = 0.f;
    int j = 0;
    for (; j + 3 < inreg; j += 4) {
        const int s0 = __shfl(mx, j, 64);
        const int s1 = __shfl(mx, j + 1, 64);
        const int s2 = __shfl(mx, j + 2, 64);
        const int s3 = __shfl(mx, j + 3, 64);
        const float a0 = __uint_as_float((unsigned)__shfl((int)my, j, 64)) * inv;
        const float a1 = __uint_as_float((unsigned)__shfl((int)my, j + 1, 64)) * inv;
        const float a2 = __uint_as_float((unsigned)__shfl((int)my, j + 2, 64)) * inv;
        const float a3 = __uint_as_float((unsigned)__shfl((int)my, j + 3, 64)) * inv;
        const bf16x2 v0 = *(const bf16x2*)(Whb + (size_t)s0 * D_FEAT + c0);
        const bf16x2 v1 = *(const bf16x2*)(Whb + (size_t)s1 * D_FEAT + c0);
        const bf16x2 v2 = *(const bf16x2*)(Whb + (size_t)s2 * D_FEAT + c0);
        const bf16x2 v3 = *(const bf16x2*)(Whb + (size_t)s3 * D_FEAT + c0);
        ax += a0 * (float)v0[0] + a1 * (float)v1[0] + a2 * (float)v2[0] + a3 * (float)v3[0];
        ay += a0 * (float)v0[1] + a1 * (float)v1[1] + a2 * (float)v2[1] + a3 * (float)v3[1];
    }
    for (; j < inreg; ++j) {
        const int s0 = __shfl(mx, j, 64);
        const float a0 = __uint_as_float((unsigned)__shfl((int)my, j, 64)) * inv;
        const bf16x2 v0 = *(const bf16x2*)(Whb + (size_t)s0 * D_FEAT + c0);
        ax += a0 * (float)v0[0];
        ay += a0 * (float)v0[1];
    }
    // cold path: degree > 64
    for (int jj = beg + 64; jj < end; ++jj) {
        const uint2 m = sorted[jj];
        const float a0 = __uint_as_float(m.y) * inv;
        const bf16x2 v0 = *(const bf16x2*)(Whb + (size_t)m.x * D_FEAT + c0);
        ax += a0 * (float)v0[0];
        ay += a0 * (float)v0[1];
    }
    f32x2 r; r[0] = ax; r[1] = ay;
    *(f32x2*)(out + (size_t)node * D_FEAT + c0) = r;
}

extern "C" void kernel_launch(void* const* d_in, const int* in_sizes, int n_in,
                              void* d_out, int out_size, void* d_ws, size_t ws_size,
                              hipStream_t stream) {
    const float* h  = (const float*)d_in[0];
    const int* eidx = (const int*)d_in[1];
    const float* ew = (const float*)d_in[2];
    const float* W  = (const float*)d_in[3];
    const float* a  = (const float*)d_in[4];
    float* out      = (float*)d_out;

    const int N = in_sizes[0] / D_FEAT;     // 100000
    const int E = in_sizes[2];              // 1600000
    const int* src = eidx;
    const int* dst = eidx + E;

    const int NCHUNK = (N + 1023) / 1024;   // 98

    // workspace layout
    char* ws = (char*)d_ws;
    size_t off = 0;
    int*    count_cur = (int*)(ws + off);   off += (size_t)N * 4;        // hist -> cursor
    float*  s_src     = (float*)(ws + off); off += (size_t)N * 4;
    float*  s_dst     = (float*)(ws + off); off += (size_t)N * 4;
    int*    row_ptr   = (int*)(ws + off);   off += (size_t)(N + 1) * 4;
    int*    blk_sums  = (int*)(ws + off);   off += 256 * 4;
    off = (off + 15) & ~(size_t)15;
    __bf16* Whi       = (__bf16*)(ws + off); off += (size_t)D_FEAT * D_FEAT * 2;
    __bf16* Wlo       = (__bf16*)(ws + off); off += (size_t)D_FEAT * D_FEAT * 2;
    uint2*  sorted    = (uint2*)(ws + off);  off += (size_t)E * 8;          // 12.8 MB
    __bf16* Whb       = (__bf16*)(ws + off); off += (size_t)N * D_FEAT * 2; // 25.6 MB

    hipMemsetAsync(count_cur, 0, (size_t)N * 4, stream);   // histogram only

    presplit_w<<<64, 256, 0, stream>>>(W, Whi, Wlo);
    gemm_s_kernel<<<(N + 63) / 64, 256, 0, stream>>>(h, Whi, Wlo, a, Whb, s_src, s_dst, N);
    hist_kernel<<<(E / 4 + 255) / 256, 256, 0, stream>>>(dst, count_cur, E);
    scan_a<<<NCHUNK, 256, 0, stream>>>(count_cur, row_ptr, blk_sums, N);
    scan_b<<<1, 256, 0, stream>>>(blk_sums, NCHUNK);
    scan_c<<<NCHUNK, 256, 0, stream>>>(row_ptr, count_cur, blk_sums, N, E);

    // 8 ranges x 128 blocks; each range group scans all edges, handles its slice
    const int SGROUPS = 128;
    const int schunk = (((E + SGROUPS - 1) / SGROUPS) + 1023) & ~1023;
    comp_scatter<<<8 * SGROUPS, 256, 0, stream>>>(src, dst, ew, s_src, s_dst,
                                                  count_cur, sorted, E, N, schunk);
    aggregate_csr<<<(N + 3) / 4, 256, 0, stream>>>(row_ptr, sorted, Whb, out, N);
}